// Round 1
// baseline (703.727 us; speedup 1.0000x reference)
//
#include <hip/hip_runtime.h>
#include <math.h>

// Problem constants
constexpr int kB   = 4;
constexpr int kL   = 1024;
constexpr int kDM  = 768;
constexpr int kDI  = 1536;   // 2*kDM
constexpr int kDS  = 16;     // D_STATE
constexpr int kDTR = 48;     // DT_RANK
constexpr int kNX  = 80;     // DTR + 2*DS
constexpr int kM   = kB * kL; // 4096
constexpr int kLTXT = 128;

// ---------------------------------------------------------------------------
// txt[b][j] = b_txt[j] + sum_k text_tokens[b,0,k] * W_txt[j,k]
// one wave per output (3072 waves, 768 blocks x 4 waves)
__global__ __launch_bounds__(256) void txt_kernel(
    const float* __restrict__ text, const float* __restrict__ Wt,
    const float* __restrict__ bt, float* __restrict__ txt)
{
    int gw = blockIdx.x * 4 + (threadIdx.x >> 6);
    int lane = threadIdx.x & 63;
    int b = gw / kDM;
    int j = gw - b * kDM;
    const float* trow = text + (size_t)b * kLTXT * kDM;  // row 0 of text tokens
    const float* wrow = Wt + (size_t)j * kDM;
    float acc = 0.f;
    #pragma unroll
    for (int k = lane; k < kDM; k += 64) acc = fmaf(trow[k], wrow[k], acc);
    #pragma unroll
    for (int o = 32; o; o >>= 1) acc += __shfl_xor(acc, o, 64);
    if (lane == 0) txt[gw] = acc + bt[j];
}

// ---------------------------------------------------------------------------
// tokens[m][k] = image[m][k] + txt[m/1024][k]   (float4 per thread)
__global__ __launch_bounds__(256) void tokens_kernel(
    const float* __restrict__ img, const float* __restrict__ txt,
    float* __restrict__ tok)
{
    int i = blockIdx.x * 256 + threadIdx.x;        // over kM*kDM/4 = 786432
    float4 a = ((const float4*)img)[i];
    int m = i / (kDM / 4);
    int k4 = i - m * (kDM / 4);
    float4 tv = ((const float4*)(txt + (size_t)(m >> 10) * kDM))[k4];
    a.x += tv.x; a.y += tv.y; a.z += tv.z; a.w += tv.w;
    ((float4*)tok)[i] = a;
}

// ---------------------------------------------------------------------------
// Generic f32 tiled GEMM: C[m][n] = sum_k A[m][k] * W[n][k]
// BM=BN=64, BK=16, 256 threads, 4x4 per thread.
// MODE 0: in_proj  -> split store x_raw / z
// MODE 1: x_proj   -> store x_dbl (N=80, NCHECK)
// MODE 2: dt_proj  -> softplus(v + bias[n]) -> dt
template<int MODE, bool NCHECK>
__global__ __launch_bounds__(256) void gemm_kernel(
    const float* __restrict__ A, int lda,
    const float* __restrict__ W, int ldw,
    int Kk, int Nn,
    float* __restrict__ out0, float* __restrict__ out1,
    const float* __restrict__ bias)
{
    __shared__ float As[16][68];
    __shared__ float Ws[16][68];
    const int t = threadIdx.x;
    const int m0 = blockIdx.x * 64;
    const int n0 = blockIdx.y * 64;
    const int lrow = t >> 2;          // 0..63
    const int lk4  = (t & 3) << 2;    // 0,4,8,12
    const int ci   = (t & 15) << 2;   // A sub-row
    const int cj   = (t >> 4) << 2;   // W sub-row
    float acc[4][4] = {};
    const float* aptr = A + (size_t)(m0 + lrow) * lda + lk4;
    const float* wptr = W + (size_t)(n0 + lrow) * ldw + lk4;
    const bool wok = !NCHECK || (n0 + lrow) < Nn;

    for (int k0 = 0; k0 < Kk; k0 += 16) {
        float4 av = *(const float4*)(aptr + k0);
        float4 wv = wok ? *(const float4*)(wptr + k0)
                        : make_float4(0.f, 0.f, 0.f, 0.f);
        if (k0) __syncthreads();
        As[lk4+0][lrow] = av.x; As[lk4+1][lrow] = av.y;
        As[lk4+2][lrow] = av.z; As[lk4+3][lrow] = av.w;
        Ws[lk4+0][lrow] = wv.x; Ws[lk4+1][lrow] = wv.y;
        Ws[lk4+2][lrow] = wv.z; Ws[lk4+3][lrow] = wv.w;
        __syncthreads();
        #pragma unroll
        for (int k = 0; k < 16; ++k) {
            const float4 a4 = *(const float4*)&As[k][ci];
            const float4 w4 = *(const float4*)&Ws[k][cj];
            const float aa[4] = {a4.x, a4.y, a4.z, a4.w};
            const float ww[4] = {w4.x, w4.y, w4.z, w4.w};
            #pragma unroll
            for (int i = 0; i < 4; ++i)
                #pragma unroll
                for (int j = 0; j < 4; ++j)
                    acc[i][j] = fmaf(aa[i], ww[j], acc[i][j]);
        }
    }

    #pragma unroll
    for (int i = 0; i < 4; ++i) {
        const int gm = m0 + ci + i;
        #pragma unroll
        for (int j = 0; j < 4; ++j) {
            const int gn = n0 + cj + j;
            if (NCHECK && gn >= Nn) continue;
            float v = acc[i][j];
            if (MODE == 0) {
                if (gn < kDI) out0[(size_t)gm * kDI + gn] = v;
                else          out1[(size_t)gm * kDI + (gn - kDI)] = v;
            } else if (MODE == 1) {
                out0[(size_t)gm * kNX + gn] = v;
            } else {
                v += bias[gn];
                v = (v > 20.f) ? v : log1pf(__expf(v));   // softplus
                out0[(size_t)gm * kDI + gn] = v;
            }
        }
    }
}

// ---------------------------------------------------------------------------
// causal depthwise conv (k=4) + SiLU: x[b,l,d] = silu(sum_j xraw[b,l-3+j,d]*w[d,j] + cb[d])
__global__ __launch_bounds__(256) void conv_silu_kernel(
    const float* __restrict__ xraw, const float* __restrict__ cw,
    const float* __restrict__ cb, float* __restrict__ xout)
{
    int idx = blockIdx.x * 256 + threadIdx.x;   // over kM*kDI
    int d = idx % kDI;
    int ml = idx / kDI;
    int l = ml & (kL - 1);
    float acc = cb[d];
    const float* base = xraw + (size_t)ml * kDI + d - 3 * (size_t)kDI;
    const float* w = cw + d * 4;
    #pragma unroll
    for (int j = 0; j < 4; ++j) {
        if (l - 3 + j >= 0) acc = fmaf(base[(size_t)j * kDI], w[j], acc);
    }
    xout[idx] = acc / (1.f + __expf(-acc));     // silu
}

// ---------------------------------------------------------------------------
// Selective scan. 16 lanes per (b,d) channel, one lane per state.
// Accumulates ysum[b,d] = sum_l (y_scan + u*D[d]) * silu(z).
__global__ __launch_bounds__(256) void scan_kernel(
    const float* __restrict__ dt, const float* __restrict__ x,
    const float* __restrict__ z, const float* __restrict__ xdbl,
    const float* __restrict__ A_log, const float* __restrict__ Dvec,
    float* __restrict__ ysum)
{
    const int t = threadIdx.x;
    const int s = t & 15;
    const int p = (blockIdx.x << 4) + (t >> 4);   // pair 0..6143
    const int b = p / kDI;
    const int d = p - b * kDI;
    const float Aval = -__expf(A_log[d * kDS + s]);
    const float Dd = Dvec[d];
    const float* dtp = dt + (size_t)b * kL * kDI + d;
    const float* xp  = x  + (size_t)b * kL * kDI + d;
    const float* zp  = z  + (size_t)b * kL * kDI + d;
    const float* bp  = xdbl + (size_t)b * kL * kNX + kDTR + s;

    float h = 0.f, acc = 0.f;
    float dtv = *dtp, uv = *xp, zv = *zp, Bv = bp[0], Cv = bp[16];
    for (int l = 0; l < kL; ++l) {
        const float c_dt = dtv, c_u = uv, c_z = zv, c_B = Bv, c_C = Cv;
        if (l < kL - 1) {       // prefetch next step
            dtp += kDI; xp += kDI; zp += kDI; bp += kNX;
            dtv = *dtp; uv = *xp; zv = *zp; Bv = bp[0]; Cv = bp[16];
        }
        const float dA = __expf(c_dt * Aval);
        h = fmaf(dA, h, (c_dt * c_u) * c_B);
        float yp = h * c_C;
        yp += __shfl_xor(yp, 1, 16);
        yp += __shfl_xor(yp, 2, 16);
        yp += __shfl_xor(yp, 4, 16);
        yp += __shfl_xor(yp, 8, 16);
        const float sz = c_z / (1.f + __expf(-c_z));   // silu(z)
        acc += (yp + c_u * Dd) * sz;
    }
    if (s == 0) ysum[p] = acc;
}

// ---------------------------------------------------------------------------
// out[b][j] = (1/L) * sum_d ysum[b][d] * Wout[j][d]; one wave per output
__global__ __launch_bounds__(256) void final_kernel(
    const float* __restrict__ ysum, const float* __restrict__ Wout,
    float* __restrict__ out)
{
    int gw = blockIdx.x * 4 + (threadIdx.x >> 6);
    int lane = threadIdx.x & 63;
    int b = gw / kDM;
    int j = gw - b * kDM;
    const float* yrow = ysum + (size_t)b * kDI;
    const float* wrow = Wout + (size_t)j * kDI;
    float acc = 0.f;
    #pragma unroll
    for (int k = lane; k < kDI; k += 64) acc = fmaf(yrow[k], wrow[k], acc);
    #pragma unroll
    for (int o = 32; o; o >>= 1) acc += __shfl_xor(acc, o, 64);
    if (lane == 0) out[gw] = acc * (1.f / (float)kL);
}

// ---------------------------------------------------------------------------
extern "C" void kernel_launch(void* const* d_in, const int* in_sizes, int n_in,
                              void* d_out, int out_size, void* d_ws, size_t ws_size,
                              hipStream_t stream)
{
    const float* image_tokens = (const float*)d_in[0];
    const float* text_tokens  = (const float*)d_in[1];
    const float* W_txt        = (const float*)d_in[2];
    const float* b_txt        = (const float*)d_in[3];
    const float* in_proj_w    = (const float*)d_in[4];
    const float* conv_w       = (const float*)d_in[5];
    const float* conv_b       = (const float*)d_in[6];
    const float* x_proj_w     = (const float*)d_in[7];
    const float* dt_proj_w    = (const float*)d_in[8];
    const float* dt_proj_b    = (const float*)d_in[9];
    const float* A_log        = (const float*)d_in[10];
    const float* Dvec         = (const float*)d_in[11];
    const float* out_proj_w   = (const float*)d_in[12];
    float* out = (float*)d_out;

    // workspace layout (floats)
    float* w = (float*)d_ws;
    float* txt  = w;                       // 3,072
    float* tok  = txt + 3072;              // 3,145,728
    float* xraw = tok + (size_t)kM * kDM;  // 6,291,456  (reused as dt)
    float* z    = xraw + (size_t)kM * kDI; // 6,291,456
    float* xbuf = z + (size_t)kM * kDI;    // 6,291,456
    float* xdbl = xbuf + (size_t)kM * kDI; // 327,680
    float* ysum = xdbl + (size_t)kM * kNX; // 6,144
    float* dt   = xraw;                    // reuse (x_raw dead after conv)

    // 1) txt projection
    txt_kernel<<<dim3(kB * kDM / 4), dim3(256), 0, stream>>>(text_tokens, W_txt, b_txt, txt);

    // 2) tokens = image + txt broadcast
    tokens_kernel<<<dim3(kM * kDM / 4 / 256), dim3(256), 0, stream>>>(image_tokens, txt, tok);

    // 3) in_proj: xz = tokens @ in_proj_w.T  (split into x_raw, z)
    gemm_kernel<0, false><<<dim3(kM / 64, 2 * kDI / 64), dim3(256), 0, stream>>>(
        tok, kDM, in_proj_w, kDM, kDM, 2 * kDI, xraw, z, nullptr);

    // 4) causal conv + silu
    conv_silu_kernel<<<dim3(kM * kDI / 256), dim3(256), 0, stream>>>(xraw, conv_w, conv_b, xbuf);

    // 5) x_proj: x_dbl = x @ x_proj_w.T   (N=80)
    gemm_kernel<1, true><<<dim3(kM / 64, 2), dim3(256), 0, stream>>>(
        xbuf, kDI, x_proj_w, kDI, kDI, kNX, xdbl, nullptr, nullptr);

    // 6) dt_proj + softplus: dt = softplus(x_dbl[:, :48] @ dt_proj_w.T + b)
    gemm_kernel<2, false><<<dim3(kM / 64, kDI / 64), dim3(256), 0, stream>>>(
        xdbl, kNX, dt_proj_w, kDTR, kDTR, kDI, dt, nullptr, dt_proj_b);

    // 7) selective scan + gating + L-sum
    scan_kernel<<<dim3(kB * kDI * kDS / 256), dim3(256), 0, stream>>>(
        dt, xbuf, z, xdbl, A_log, Dvec, ysum);

    // 8) out = (ysum/L) @ out_proj_w.T
    final_kernel<<<dim3(kB * kDM / 4), dim3(256), 0, stream>>>(ysum, out_proj_w, out);
}

// Round 2
// 253.827 us; speedup vs baseline: 2.7725x; 2.7725x over previous
//
#include <hip/hip_runtime.h>
#include <math.h>

// Problem constants
constexpr int kB   = 4;
constexpr int kL   = 1024;
constexpr int kDM  = 768;
constexpr int kDI  = 1536;   // 2*kDM
constexpr int kDS  = 16;     // D_STATE
constexpr int kDTR = 48;     // DT_RANK
constexpr int kNX  = 80;     // DTR + 2*DS
constexpr int kM   = kB * kL; // 4096
constexpr int kLTXT = 128;

typedef __attribute__((ext_vector_type(8))) short bf16x8;
typedef __attribute__((ext_vector_type(4))) float f32x4;

__device__ inline unsigned short f2bf(float f) {
    unsigned u = __float_as_uint(f);
    u = (u + 0x7FFFu + ((u >> 16) & 1u)) >> 16;   // RNE
    return (unsigned short)u;
}

// ---------------------------------------------------------------------------
// txt[b][j] = b_txt[j] + sum_k text_tokens[b,0,k] * W_txt[j,k]
__global__ __launch_bounds__(256) void txt_kernel(
    const float* __restrict__ text, const float* __restrict__ Wt,
    const float* __restrict__ bt, float* __restrict__ txt)
{
    int gw = blockIdx.x * 4 + (threadIdx.x >> 6);
    int lane = threadIdx.x & 63;
    int b = gw / kDM;
    int j = gw - b * kDM;
    const float* trow = text + (size_t)b * kLTXT * kDM;
    const float* wrow = Wt + (size_t)j * kDM;
    float acc = 0.f;
    for (int k = lane; k < kDM; k += 64) acc = fmaf(trow[k], wrow[k], acc);
    #pragma unroll
    for (int o = 32; o; o >>= 1) acc += __shfl_xor(acc, o, 64);
    if (lane == 0) txt[gw] = acc + bt[j];
}

// ---------------------------------------------------------------------------
// tokens_bf16[m][k] = bf16(image[m][k] + txt[m/1024][k])
__global__ __launch_bounds__(256) void tokens_bf16_kernel(
    const float* __restrict__ img, const float* __restrict__ txt,
    unsigned short* __restrict__ tok)
{
    int i = blockIdx.x * 256 + threadIdx.x;        // over kM*kDM/4
    float4 a = ((const float4*)img)[i];
    int m = i / (kDM / 4);
    int k4 = i - m * (kDM / 4);
    float4 tv = ((const float4*)(txt + (size_t)(m >> 10) * kDM))[k4];
    ushort4 o;
    o.x = f2bf(a.x + tv.x); o.y = f2bf(a.y + tv.y);
    o.z = f2bf(a.z + tv.z); o.w = f2bf(a.w + tv.w);
    ((ushort4*)tok)[i] = o;
}

// ---------------------------------------------------------------------------
// cast in_proj_w (f32, [3072][768]) -> bf16
__global__ __launch_bounds__(256) void castw_kernel(
    const float* __restrict__ w, unsigned short* __restrict__ o, int n4)
{
    int i = blockIdx.x * 256 + threadIdx.x;
    if (i >= n4) return;
    float4 a = ((const float4*)w)[i];
    ushort4 v;
    v.x = f2bf(a.x); v.y = f2bf(a.y); v.z = f2bf(a.z); v.w = f2bf(a.w);
    ((ushort4*)o)[i] = v;
}

// ---------------------------------------------------------------------------
// bf16 MFMA GEMM for in_proj: C[m][n] = sum_k A[m][k]*W[n][k]
// M=4096, N=3072, K=768. BM=BN=128, BK=32, 256 threads (4 waves, 2x2).
// n<1536 -> xraw; n>=1536 -> g = silu(v)
__global__ __launch_bounds__(256) void mfma_inproj_kernel(
    const unsigned short* __restrict__ A, const unsigned short* __restrict__ W,
    float* __restrict__ xout, float* __restrict__ gout)
{
    __shared__ unsigned short Asm[2][128][32];
    __shared__ unsigned short Wsm[2][128][32];
    const int t = threadIdx.x;
    const int m0 = blockIdx.x * 128;
    const int n0 = blockIdx.y * 128;
    const int lane = t & 63;
    const int wv = t >> 6;
    const int wr = wv >> 1, wc = wv & 1;

    // staging: thread t loads 32B (two 16B) at row t>>1, halfrow t&1
    const int arow = t >> 1, acol = (t & 1) * 16;
    const unsigned short* ap = A + (size_t)(m0 + arow) * kDM + acol;
    const unsigned short* wp = W + (size_t)(n0 + arow) * kDM + acol;
    uint4 va0, va1, vw0, vw1;
    auto load_tiles = [&](int k0) {
        va0 = *(const uint4*)(ap + k0);
        va1 = *(const uint4*)(ap + k0 + 8);
        vw0 = *(const uint4*)(wp + k0);
        vw1 = *(const uint4*)(wp + k0 + 8);
    };
    auto store_tiles = [&](int buf) {
        *(uint4*)&Asm[buf][arow][acol]     = va0;
        *(uint4*)&Asm[buf][arow][acol + 8] = va1;
        *(uint4*)&Wsm[buf][arow][acol]     = vw0;
        *(uint4*)&Wsm[buf][arow][acol + 8] = vw1;
    };

    f32x4 acc[4][4] = {};
    const int fr = lane & 15;
    const int fk = (lane >> 4) * 8;

    load_tiles(0);
    store_tiles(0);
    __syncthreads();

    int buf = 0;
    for (int k0 = 0; k0 < kDM; k0 += 32) {
        if (k0 + 32 < kDM) load_tiles(k0 + 32);
        bf16x8 af[4], wf[4];
        #pragma unroll
        for (int i = 0; i < 4; ++i)
            af[i] = *(const bf16x8*)&Asm[buf][wr * 64 + i * 16 + fr][fk];
        #pragma unroll
        for (int j = 0; j < 4; ++j)
            wf[j] = *(const bf16x8*)&Wsm[buf][wc * 64 + j * 16 + fr][fk];
        #pragma unroll
        for (int i = 0; i < 4; ++i)
            #pragma unroll
            for (int j = 0; j < 4; ++j)
                acc[i][j] = __builtin_amdgcn_mfma_f32_16x16x32_bf16(af[i], wf[j], acc[i][j], 0, 0, 0);
        if (k0 + 32 < kDM) {
            __syncthreads();
            store_tiles(buf ^ 1);
            __syncthreads();
            buf ^= 1;
        }
    }

    // epilogue: row = (lane>>4)*4 + q, col = lane&15  (per 16x16 fragment)
    const int erow = (lane >> 4) * 4;
    const int ecol = lane & 15;
    #pragma unroll
    for (int i = 0; i < 4; ++i) {
        #pragma unroll
        for (int j = 0; j < 4; ++j) {
            const int gn = n0 + wc * 64 + j * 16 + ecol;
            #pragma unroll
            for (int q = 0; q < 4; ++q) {
                const int gm = m0 + wr * 64 + i * 16 + erow + q;
                float v = acc[i][j][q];
                if (gn < kDI) {
                    xout[(size_t)gm * kDI + gn] = v;
                } else {
                    gout[(size_t)gm * kDI + (gn - kDI)] = v / (1.f + __expf(-v));
                }
            }
        }
    }
}

// ---------------------------------------------------------------------------
// f32 tiled GEMM (small ones): C[m][n] = sum_k A[m][k]*W[n][k]
// MODE 1: x_proj -> x_dbl (N=80, NCHECK). MODE 2: dt_proj -> softplus -> dt
template<int MODE, bool NCHECK>
__global__ __launch_bounds__(256) void gemm_kernel(
    const float* __restrict__ A, int lda,
    const float* __restrict__ W, int ldw,
    int Kk, int Nn,
    float* __restrict__ out0, const float* __restrict__ bias)
{
    __shared__ float As[16][68];
    __shared__ float Ws[16][68];
    const int t = threadIdx.x;
    const int m0 = blockIdx.x * 64;
    const int n0 = blockIdx.y * 64;
    const int lrow = t >> 2;
    const int lk4  = (t & 3) << 2;
    const int ci   = (t & 15) << 2;
    const int cj   = (t >> 4) << 2;
    float acc[4][4] = {};
    const float* aptr = A + (size_t)(m0 + lrow) * lda + lk4;
    const float* wptr = W + (size_t)(n0 + lrow) * ldw + lk4;
    const bool wok = !NCHECK || (n0 + lrow) < Nn;

    for (int k0 = 0; k0 < Kk; k0 += 16) {
        float4 av = *(const float4*)(aptr + k0);
        float4 wv = wok ? *(const float4*)(wptr + k0)
                        : make_float4(0.f, 0.f, 0.f, 0.f);
        if (k0) __syncthreads();
        As[lk4+0][lrow] = av.x; As[lk4+1][lrow] = av.y;
        As[lk4+2][lrow] = av.z; As[lk4+3][lrow] = av.w;
        Ws[lk4+0][lrow] = wv.x; Ws[lk4+1][lrow] = wv.y;
        Ws[lk4+2][lrow] = wv.z; Ws[lk4+3][lrow] = wv.w;
        __syncthreads();
        #pragma unroll
        for (int k = 0; k < 16; ++k) {
            const float4 a4 = *(const float4*)&As[k][ci];
            const float4 w4 = *(const float4*)&Ws[k][cj];
            const float aa[4] = {a4.x, a4.y, a4.z, a4.w};
            const float ww[4] = {w4.x, w4.y, w4.z, w4.w};
            #pragma unroll
            for (int i = 0; i < 4; ++i)
                #pragma unroll
                for (int j = 0; j < 4; ++j)
                    acc[i][j] = fmaf(aa[i], ww[j], acc[i][j]);
        }
    }

    #pragma unroll
    for (int i = 0; i < 4; ++i) {
        const int gm = m0 + ci + i;
        #pragma unroll
        for (int j = 0; j < 4; ++j) {
            const int gn = n0 + cj + j;
            if (NCHECK && gn >= Nn) continue;
            float v = acc[i][j];
            if (MODE == 1) {
                out0[(size_t)gm * kNX + gn] = v;
            } else {
                v += bias[gn];
                v = (v > 20.f) ? v : log1pf(__expf(v));
                out0[(size_t)gm * kDI + gn] = v;
            }
        }
    }
}

// ---------------------------------------------------------------------------
// causal depthwise conv (k=4) + SiLU
__global__ __launch_bounds__(256) void conv_silu_kernel(
    const float* __restrict__ xraw, const float* __restrict__ cw,
    const float* __restrict__ cb, float* __restrict__ xout)
{
    int idx = blockIdx.x * 256 + threadIdx.x;   // over kM*kDI
    int d = idx % kDI;
    int ml = idx / kDI;
    int l = ml & (kL - 1);
    float acc = cb[d];
    const float* base = xraw + (size_t)ml * kDI + d - 3 * (size_t)kDI;
    const float* w = cw + d * 4;
    #pragma unroll
    for (int j = 0; j < 4; ++j) {
        if (l - 3 + j >= 0) acc = fmaf(base[(size_t)j * kDI], w[j], acc);
    }
    xout[idx] = acc / (1.f + __expf(-acc));
}

// ---------------------------------------------------------------------------
// Selective scan v2. Block = 256 threads = 16 channels x 16 states, one b.
// LDS double-buffered 64-step chunks; no per-step shuffles:
//   acc_s = sum_l h_{l,s} * C_{l,s} * g_l ;  ug = sum_l u_l * g_l
//   ysum[b,d] = sum_s acc_s + D_d * ug
constexpr int kT  = 64;          // steps per chunk
constexpr int kNC = kL / kT;     // 16 chunks

__global__ __launch_bounds__(256) void scan2_kernel(
    const float* __restrict__ dt, const float* __restrict__ x,
    const float* __restrict__ g, const float* __restrict__ xdbl,
    const float* __restrict__ A_log, const float* __restrict__ Dvec,
    float* __restrict__ ysum)
{
    __shared__ float dtS[2][kT][16];
    __shared__ float uS [2][kT][16];
    __shared__ float gS [2][kT][16];
    __shared__ float BS [2][kT][16];
    __shared__ float CS [2][kT][16];
    const int t = threadIdx.x;
    const int b  = blockIdx.x / 96;            // 96 blocks per batch
    const int d0 = (blockIdx.x % 96) * 16;

    // staging: thread t loads float4 at chunk-row sl, col sc
    const int sl = t >> 2, sc = (t & 3) << 2;
    const float* dt_base = dt + ((size_t)b << 10) * kDI + d0;
    const float* x_base  = x  + ((size_t)b << 10) * kDI + d0;
    const float* g_base  = g  + ((size_t)b << 10) * kDI + d0;
    const float* bc_base = xdbl + ((size_t)b << 10) * kNX + kDTR;

    const int s = t & 15;     // state
    const int c = t >> 4;     // channel in block
    const int d = d0 + c;
    const float Aval = -__expf(A_log[d * kDS + s]);

    float4 r_dt, r_u, r_g, r_B, r_C;
    auto load_chunk = [&](int l0) {
        r_dt = *(const float4*)(dt_base + (size_t)(l0 + sl) * kDI + sc);
        r_u  = *(const float4*)(x_base  + (size_t)(l0 + sl) * kDI + sc);
        r_g  = *(const float4*)(g_base  + (size_t)(l0 + sl) * kDI + sc);
        r_B  = *(const float4*)(bc_base + (size_t)(l0 + sl) * kNX + sc);
        r_C  = *(const float4*)(bc_base + (size_t)(l0 + sl) * kNX + 16 + sc);
    };
    auto store_chunk = [&](int bf) {
        *(float4*)&dtS[bf][sl][sc] = r_dt;
        *(float4*)&uS [bf][sl][sc] = r_u;
        *(float4*)&gS [bf][sl][sc] = r_g;
        *(float4*)&BS [bf][sl][sc] = r_B;
        *(float4*)&CS [bf][sl][sc] = r_C;
    };

    load_chunk(0);
    store_chunk(0);
    __syncthreads();

    float h = 0.f, acc = 0.f, ug = 0.f;
    for (int ck = 0; ck < kNC; ++ck) {
        const int bu = ck & 1;
        if (ck + 1 < kNC) load_chunk((ck + 1) * kT);
        #pragma unroll 4
        for (int i = 0; i < kT; ++i) {
            const float dtv = dtS[bu][i][c];
            const float uv  = uS [bu][i][c];
            const float gv  = gS [bu][i][c];
            const float Bv  = BS [bu][i][s];
            const float Cv  = CS [bu][i][s];
            const float dA  = __expf(dtv * Aval);
            h   = fmaf(dA, h, dtv * uv * Bv);
            acc = fmaf(h * Cv, gv, acc);
            ug  = fmaf(uv, gv, ug);
        }
        if (ck + 1 < kNC) {
            __syncthreads();
            store_chunk(bu ^ 1);
            __syncthreads();
        }
    }

    // reduce acc over the 16 states of this channel (once, at the end)
    #pragma unroll
    for (int o = 1; o < 16; o <<= 1) acc += __shfl_xor(acc, o, 64);
    if (s == 0) ysum[(size_t)b * kDI + d] = acc + Dvec[d] * ug;
}

// ---------------------------------------------------------------------------
// out[b][j] = (1/L) * sum_d ysum[b][d] * Wout[j][d]
__global__ __launch_bounds__(256) void final_kernel(
    const float* __restrict__ ysum, const float* __restrict__ Wout,
    float* __restrict__ out)
{
    int gw = blockIdx.x * 4 + (threadIdx.x >> 6);
    int lane = threadIdx.x & 63;
    int b = gw / kDM;
    int j = gw - b * kDM;
    const float* yrow = ysum + (size_t)b * kDI;
    const float* wrow = Wout + (size_t)j * kDI;
    float acc = 0.f;
    for (int k = lane; k < kDI; k += 64) acc = fmaf(yrow[k], wrow[k], acc);
    #pragma unroll
    for (int o = 32; o; o >>= 1) acc += __shfl_xor(acc, o, 64);
    if (lane == 0) out[gw] = acc * (1.f / (float)kL);
}

// ---------------------------------------------------------------------------
extern "C" void kernel_launch(void* const* d_in, const int* in_sizes, int n_in,
                              void* d_out, int out_size, void* d_ws, size_t ws_size,
                              hipStream_t stream)
{
    const float* image_tokens = (const float*)d_in[0];
    const float* text_tokens  = (const float*)d_in[1];
    const float* W_txt        = (const float*)d_in[2];
    const float* b_txt        = (const float*)d_in[3];
    const float* in_proj_w    = (const float*)d_in[4];
    const float* conv_w       = (const float*)d_in[5];
    const float* conv_b       = (const float*)d_in[6];
    const float* x_proj_w     = (const float*)d_in[7];
    const float* dt_proj_w    = (const float*)d_in[8];
    const float* dt_proj_b    = (const float*)d_in[9];
    const float* A_log        = (const float*)d_in[10];
    const float* Dvec         = (const float*)d_in[11];
    const float* out_proj_w   = (const float*)d_in[12];
    float* out = (float*)d_out;

    // workspace layout (bytes, all 256B-aligned)
    char* p = (char*)d_ws;
    float* txt = (float*)p;                       p += 12288;
    unsigned short* tokb = (unsigned short*)p;    p += (size_t)kM * kDM * 2;       // 6.3 MB
    unsigned short* wb   = (unsigned short*)p;    p += (size_t)2 * kDI * kDM * 2;  // 4.7 MB
    float* xraw = (float*)p;                      p += (size_t)kM * kDI * 4;       // 25.2 MB (reused as dt)
    float* gbuf = (float*)p;                      p += (size_t)kM * kDI * 4;       // 25.2 MB
    float* xbuf = (float*)p;                      p += (size_t)kM * kDI * 4;       // 25.2 MB
    float* xdbl = (float*)p;                      p += (size_t)kM * kNX * 4;       // 1.3 MB
    float* ysum = (float*)p;                      p += (size_t)kB * kDI * 4;
    float* dt = xraw;   // xraw dead after conv

    // 1) txt projection
    txt_kernel<<<dim3(kB * kDM / 4), dim3(256), 0, stream>>>(text_tokens, W_txt, b_txt, txt);

    // 2) tokens = bf16(image + txt)
    tokens_bf16_kernel<<<dim3(kM * kDM / 4 / 256), dim3(256), 0, stream>>>(image_tokens, txt, tokb);

    // 3) cast in_proj_w to bf16
    castw_kernel<<<dim3((2 * kDI * kDM / 4 + 255) / 256), dim3(256), 0, stream>>>(
        in_proj_w, wb, 2 * kDI * kDM / 4);

    // 4) in_proj (bf16 MFMA): x half -> xraw, z half -> g = silu(z)
    mfma_inproj_kernel<<<dim3(kM / 128, 2 * kDI / 128), dim3(256), 0, stream>>>(
        tokb, wb, xraw, gbuf);

    // 5) causal conv + silu
    conv_silu_kernel<<<dim3(kM * kDI / 256), dim3(256), 0, stream>>>(xraw, conv_w, conv_b, xbuf);

    // 6) x_proj: x_dbl = x @ x_proj_w.T   (N=80)
    gemm_kernel<1, true><<<dim3(kM / 64, 2), dim3(256), 0, stream>>>(
        xbuf, kDI, x_proj_w, kDI, kDI, kNX, xdbl, nullptr);

    // 7) dt_proj + softplus
    gemm_kernel<2, false><<<dim3(kM / 64, kDI / 64), dim3(256), 0, stream>>>(
        xdbl, kNX, dt_proj_w, kDTR, kDTR, kDI, dt, dt_proj_b);

    // 8) selective scan + gating + L-sum
    scan2_kernel<<<dim3(kB * 96), dim3(256), 0, stream>>>(
        dt, xbuf, gbuf, xdbl, A_log, Dvec, ysum);

    // 9) out = (ysum/L) @ out_proj_w.T
    final_kernel<<<dim3(kB * kDM / 4), dim3(256), 0, stream>>>(ysum, out_proj_w, out);
}